// Round 1
// baseline (4557.477 us; speedup 1.0000x reference)
//
#include <hip/hip_runtime.h>
#include <hip/hip_fp16.h>

// Problem constants (fixed by setup_inputs)
#define E_TOTAL 524288
#define RRELU_SLOPE 0.22916666666666666f

typedef float f32x4 __attribute__((ext_vector_type(4)));
typedef short short8_t __attribute__((ext_vector_type(8)));
typedef _Float16 h2_t __attribute__((ext_vector_type(2)));

#if defined(__has_builtin)
# if __has_builtin(__builtin_amdgcn_fdot2)
#  define HAVE_FDOT2 1
# endif
#endif

__device__ inline unsigned short f2bf(float x) {
  unsigned int u = __float_as_uint(x);
  u += 0x7FFFu + ((u >> 16) & 1u);   // RNE
  return (unsigned short)(u >> 16);
}

__device__ inline unsigned int pack_h2(float a, float b) {
  __half2 h = __floats2half2_rn(a, b);
  return __builtin_bit_cast(unsigned int, h);
}

__device__ inline float dot2f(unsigned int a, unsigned int b, float c) {
#ifdef HAVE_FDOT2
  return __builtin_amdgcn_fdot2(__builtin_bit_cast(h2_t, a),
                                __builtin_bit_cast(h2_t, b), c, false);
#else
  h2_t av = __builtin_bit_cast(h2_t, a);
  h2_t bv = __builtin_bit_cast(h2_t, b);
  return c + (float)av[0] * (float)bv[0] + (float)av[1] * (float)bv[1];
#endif
}

__device__ inline float dot4(float4 a, float4 b) {
  return a.x * b.x + a.y * b.y + a.z * b.z + a.w * b.w;
}

// ---------------------------------------------------------------------------
// Generic bf16-MFMA GEMM: C[M,N] = act(A[M,K](fp32) @ B[K,N] + bias)
// B passed pre-transposed+converted: BT[N][K] bf16. Grid: (M/128, N/128).
// act: 0=none, 1=relu, 2=rrelu
// ---------------------------------------------------------------------------
__global__ __launch_bounds__(256) void gemm_bf16(
    const float* __restrict__ A, int lda,
    const unsigned short* __restrict__ BT,
    const float* __restrict__ bias,
    float* __restrict__ C, int ldc,
    int K, int act)
{
  __shared__ unsigned short As[128][32];
  __shared__ unsigned short Bs[128][32];
  const int tid = threadIdx.x;
  const int bm = blockIdx.x, bn = blockIdx.y;
  const int w = tid >> 6, l = tid & 63;
  const int wm = (w & 1) * 64, wn = (w >> 1) * 64;
  const int q = l >> 4, r = l & 15;

  f32x4 acc[4][4];
  for (int i = 0; i < 4; ++i)
    for (int j = 0; j < 4; ++j)
      acc[i][j] = (f32x4){0.f, 0.f, 0.f, 0.f};

  const int sm = tid >> 1;        // 0..127 (row within tile)
  const int sk = (tid & 1) * 16;  // 0 or 16
  const float* ap = A + (size_t)(bm * 128 + sm) * lda + sk;
  const unsigned short* bp = BT + (size_t)(bn * 128 + sm) * K + sk;

  for (int k0 = 0; k0 < K; k0 += 32) {
    // stage A (fp32 -> bf16)
    float4 f0 = *(const float4*)(ap + k0);
    float4 f1 = *(const float4*)(ap + k0 + 4);
    float4 f2 = *(const float4*)(ap + k0 + 8);
    float4 f3 = *(const float4*)(ap + k0 + 12);
    uint4 p0, p1;
    p0.x = (unsigned)f2bf(f0.x) | ((unsigned)f2bf(f0.y) << 16);
    p0.y = (unsigned)f2bf(f0.z) | ((unsigned)f2bf(f0.w) << 16);
    p0.z = (unsigned)f2bf(f1.x) | ((unsigned)f2bf(f1.y) << 16);
    p0.w = (unsigned)f2bf(f1.z) | ((unsigned)f2bf(f1.w) << 16);
    p1.x = (unsigned)f2bf(f2.x) | ((unsigned)f2bf(f2.y) << 16);
    p1.y = (unsigned)f2bf(f2.z) | ((unsigned)f2bf(f2.w) << 16);
    p1.z = (unsigned)f2bf(f3.x) | ((unsigned)f2bf(f3.y) << 16);
    p1.w = (unsigned)f2bf(f3.z) | ((unsigned)f2bf(f3.w) << 16);
    *(uint4*)&As[sm][sk] = p0;
    *(uint4*)&As[sm][sk + 8] = p1;
    // stage B (already bf16, [n][k] layout)
    uint4 b0 = *(const uint4*)(bp + k0);
    uint4 b1 = *(const uint4*)(bp + k0 + 8);
    *(uint4*)&Bs[sm][sk] = b0;
    *(uint4*)&Bs[sm][sk + 8] = b1;
    __syncthreads();

    short8_t af[4], bfr[4];
    for (int mt = 0; mt < 4; ++mt)
      af[mt] = *(const short8_t*)&As[wm + mt * 16 + r][q * 8];
    for (int nt = 0; nt < 4; ++nt)
      bfr[nt] = *(const short8_t*)&Bs[wn + nt * 16 + r][q * 8];
    for (int mt = 0; mt < 4; ++mt)
      for (int nt = 0; nt < 4; ++nt)
        acc[mt][nt] = __builtin_amdgcn_mfma_f32_16x16x32_bf16(
            af[mt], bfr[nt], acc[mt][nt], 0, 0, 0);
    __syncthreads();
  }

  // epilogue: C/D layout col=l&15, row=(l>>4)*4+reg
  for (int nt = 0; nt < 4; ++nt) {
    int gc = bn * 128 + wn + nt * 16 + r;
    float bv = bias ? bias[gc] : 0.f;
    for (int mt = 0; mt < 4; ++mt) {
      int gm = bm * 128 + wm + mt * 16 + q * 4;
      for (int rr = 0; rr < 4; ++rr) {
        float v = acc[mt][nt][rr] + bv;
        if (act == 1) v = fmaxf(v, 0.f);
        else if (act == 2) v = (v >= 0.f) ? v : v * RRELU_SLOPE;
        C[(size_t)(gm + rr) * ldc + gc] = v;
      }
    }
  }
}

// ---------------------------------------------------------------------------
// Edge message + aggregate + update.
// y[T,512] = [x@Wn+bm | x@Ws+bs]. One block per (graph, dim-half).
// Lane owns dims dbase+l and dbase+l+64 -> agg LDS banks 2-way only.
// msg = relu(y[src,d] + sum_k ea[k]*We[k][d]);  agg[dst,d] += msg
// x_out = relu(y[.,256+d] + agg)
// ---------------------------------------------------------------------------
__global__ __launch_bounds__(1024) void edge_conv(
    const float* __restrict__ y,
    const int* __restrict__ eidx,         // [2, E]
    const unsigned int* __restrict__ ea_h2, // [E, 8] half2 pairs
    const unsigned int* __restrict__ We_h2, // [8, 256] half2 (k-pairs)
    float* __restrict__ x_out)
{
  __shared__ float agg[64 * 128];
  const int g = blockIdx.x >> 1;
  const int dbase = (blockIdx.x & 1) * 128;
  const int tid = threadIdx.x;
  for (int i = tid; i < 64 * 128; i += 1024) agg[i] = 0.f;
  const int l = tid & 63;
  const int d0 = dbase + l, d1 = dbase + l + 64;
  unsigned int we0[8], we1[8];
#pragma unroll
  for (int j = 0; j < 8; ++j) {
    we0[j] = We_h2[j * 256 + d0];
    we1[j] = We_h2[j * 256 + d1];
  }
  __syncthreads();
  const int w = tid >> 6;
  const int ebase = g * 2048 + w * 128;
  for (int e = 0; e < 128; ++e) {
    int ge = ebase + e;
    int src = eidx[ge];
    int dst = eidx[E_TOTAL + ge];
    int dl = dst & 63;
    const float* yr = y + (size_t)src * 512;
    float m0 = yr[d0];
    float m1 = yr[d1];
    uint4 ea0 = *(const uint4*)(ea_h2 + (size_t)ge * 8);
    uint4 ea1 = *(const uint4*)(ea_h2 + (size_t)ge * 8 + 4);
    m0 = dot2f(ea0.x, we0[0], m0); m1 = dot2f(ea0.x, we1[0], m1);
    m0 = dot2f(ea0.y, we0[1], m0); m1 = dot2f(ea0.y, we1[1], m1);
    m0 = dot2f(ea0.z, we0[2], m0); m1 = dot2f(ea0.z, we1[2], m1);
    m0 = dot2f(ea0.w, we0[3], m0); m1 = dot2f(ea0.w, we1[3], m1);
    m0 = dot2f(ea1.x, we0[4], m0); m1 = dot2f(ea1.x, we1[4], m1);
    m0 = dot2f(ea1.y, we0[5], m0); m1 = dot2f(ea1.y, we1[5], m1);
    m0 = dot2f(ea1.z, we0[6], m0); m1 = dot2f(ea1.z, we1[6], m1);
    m0 = dot2f(ea1.w, we0[7], m0); m1 = dot2f(ea1.w, we1[7], m1);
    m0 = fmaxf(m0, 0.f);
    m1 = fmaxf(m1, 0.f);
    atomicAdd(&agg[dl * 128 + l], m0);
    atomicAdd(&agg[dl * 128 + l + 64], m1);
  }
  __syncthreads();
  for (int i = tid; i < 64 * 128; i += 1024) {
    int n = i >> 7, dd = i & 127;
    float v = y[(size_t)(g * 64 + n) * 512 + 256 + dbase + dd] + agg[i];
    x_out[(size_t)(g * 64 + n) * 256 + dbase + dd] = fmaxf(v, 0.f);
  }
}

// ---------------------------------------------------------------------------
// dot_pool: per graph, item = X1 @ X2^T [64x64]; write max & mean to fusion.
// ---------------------------------------------------------------------------
__global__ __launch_bounds__(256) void dot_pool_k(
    const float* __restrict__ x1, const float* __restrict__ x2,
    float* __restrict__ fusion, int step)
{
  __shared__ float s1[64][68];
  __shared__ float s2[64][68];
  __shared__ float redm[4], reds[4];
  const int g = blockIdx.x;
  const int tid = threadIdx.x;
  const int ti = (tid & 15) * 4;
  const int tj = (tid >> 4) * 4;
  float acc[4][4] = {};
  for (int kc = 0; kc < 256; kc += 64) {
    for (int rr = 0; rr < 4; ++rr) {
      int lin = tid + rr * 256;
      int n = lin >> 4, k4 = (lin & 15) * 4;
      *(float4*)&s1[n][k4] = *(const float4*)(x1 + (size_t)(g * 64 + n) * 256 + kc + k4);
      *(float4*)&s2[n][k4] = *(const float4*)(x2 + (size_t)(g * 64 + n) * 256 + kc + k4);
    }
    __syncthreads();
    for (int kk = 0; kk < 64; kk += 4) {
      float4 a0 = *(const float4*)&s1[ti + 0][kk];
      float4 a1 = *(const float4*)&s1[ti + 1][kk];
      float4 a2 = *(const float4*)&s1[ti + 2][kk];
      float4 a3 = *(const float4*)&s1[ti + 3][kk];
      float4 b0 = *(const float4*)&s2[tj + 0][kk];
      float4 b1 = *(const float4*)&s2[tj + 1][kk];
      float4 b2 = *(const float4*)&s2[tj + 2][kk];
      float4 b3 = *(const float4*)&s2[tj + 3][kk];
      acc[0][0] += dot4(a0, b0); acc[0][1] += dot4(a0, b1);
      acc[0][2] += dot4(a0, b2); acc[0][3] += dot4(a0, b3);
      acc[1][0] += dot4(a1, b0); acc[1][1] += dot4(a1, b1);
      acc[1][2] += dot4(a1, b2); acc[1][3] += dot4(a1, b3);
      acc[2][0] += dot4(a2, b0); acc[2][1] += dot4(a2, b1);
      acc[2][2] += dot4(a2, b2); acc[2][3] += dot4(a2, b3);
      acc[3][0] += dot4(a3, b0); acc[3][1] += dot4(a3, b1);
      acc[3][2] += dot4(a3, b2); acc[3][3] += dot4(a3, b3);
    }
    __syncthreads();
  }
  float mymax = -1e30f, mysum = 0.f;
  for (int i = 0; i < 4; ++i)
    for (int j = 0; j < 4; ++j) {
      mymax = fmaxf(mymax, acc[i][j]);
      mysum += acc[i][j];
    }
  for (int off = 32; off; off >>= 1) {
    mymax = fmaxf(mymax, __shfl_down(mymax, off, 64));
    mysum += __shfl_down(mysum, off, 64);
  }
  if ((tid & 63) == 0) { redm[tid >> 6] = mymax; reds[tid >> 6] = mysum; }
  __syncthreads();
  if (tid == 0) {
    float gm = fmaxf(fmaxf(redm[0], redm[1]), fmaxf(redm[2], redm[3]));
    float gs = reds[0] + reds[1] + reds[2] + reds[3];
    fusion[g * 6 + step * 2] = gm;
    fusion[g * 6 + step * 2 + 1] = gs * (1.f / 4096.f);
  }
}

// ---------------------------------------------------------------------------
// readout: R[g] = [mean(256) | sum(256) | top3-by-last-col rows (3x256)]
// Stable tie-break: strict '>' picks lowest index first (matches stable argsort)
// ---------------------------------------------------------------------------
__global__ __launch_bounds__(256) void readout_assemble(
    const float* __restrict__ xm, float* __restrict__ R)
{
  __shared__ float lastcol[64];
  __shared__ int topi[3];
  const int g = blockIdx.x, d = threadIdx.x;
  float s = 0.f;
  for (int n = 0; n < 64; ++n) s += xm[(size_t)(g * 64 + n) * 256 + d];
  R[(size_t)g * 1280 + d] = s * (1.f / 64.f);
  R[(size_t)g * 1280 + 256 + d] = s;
  if (d < 64) lastcol[d] = xm[(size_t)(g * 64 + d) * 256 + 255];
  __syncthreads();
  if (d == 0) {
    unsigned long long used = 0;
    for (int j = 0; j < 3; ++j) {
      float best = -1e30f;
      int bi = 0;
      for (int n = 0; n < 64; ++n) {
        if ((used >> n) & 1ull) continue;
        if (lastcol[n] > best) { best = lastcol[n]; bi = n; }
      }
      used |= (1ull << bi);
      topi[j] = bi;
    }
  }
  __syncthreads();
  for (int j = 0; j < 3; ++j)
    R[(size_t)g * 1280 + 512 + j * 256 + d] =
        xm[(size_t)(g * 64 + topi[j]) * 256 + d];
}

// ---------------------------------------------------------------------------
// final head: out = (cat(outm1, outm2, fusion) @ Wo1 + bo1) @ Wo2 + bo2
// ---------------------------------------------------------------------------
__global__ __launch_bounds__(256) void final_head(
    const float* __restrict__ outm1, const float* __restrict__ outm2,
    const float* __restrict__ fusion,
    const float* __restrict__ Wo1, const float* __restrict__ bo1,
    const float* __restrict__ Wo2, const float* __restrict__ bo2,
    float* __restrict__ out)
{
  __shared__ float cat[520];
  __shared__ float r0s[4], r1s[4];
  const int g = blockIdx.x, t = threadIdx.x;
  cat[t] = outm1[(size_t)g * 256 + t];
  cat[256 + t] = outm2[(size_t)g * 256 + t];
  if (t < 6) cat[512 + t] = fusion[g * 6 + t];
  __syncthreads();
  float acc = bo1[t];
  for (int k = 0; k < 518; ++k) acc = fmaf(cat[k], Wo1[(size_t)k * 256 + t], acc);
  float p0 = acc * Wo2[t * 2];
  float p1 = acc * Wo2[t * 2 + 1];
  for (int off = 32; off; off >>= 1) {
    p0 += __shfl_down(p0, off, 64);
    p1 += __shfl_down(p1, off, 64);
  }
  if ((t & 63) == 0) { r0s[t >> 6] = p0; r1s[t >> 6] = p1; }
  __syncthreads();
  if (t == 0) {
    out[g * 2] = r0s[0] + r0s[1] + r0s[2] + r0s[3] + bo2[0];
    out[g * 2 + 1] = r1s[0] + r1s[1] + r1s[2] + r1s[3] + bo2[1];
  }
}

// ---------------------------------------------------------------------------
// Prep kernels (run every launch; ws is re-poisoned each call)
// ---------------------------------------------------------------------------
// src [K][256] fp32 -> dst [256][K] bf16. grid = K blocks x 256.
__global__ void transpose_cvt256(const float* __restrict__ src,
                                 unsigned short* __restrict__ dst, int K)
{
  int k = blockIdx.x, n = threadIdx.x;
  dst[n * K + k] = f2bf(src[k * 256 + n]);
}

__global__ void misc_prep(
    const float* bm1, const float* bs1, const float* bm2, const float* bs2,
    const float* We1, const float* We2,
    float* bcat1, float* bcat2,
    unsigned int* weh1, unsigned int* weh2)
{
  int idx = blockIdx.x * 256 + threadIdx.x;  // grid 20 -> 5120
  if (idx < 512) {
    bcat1[idx] = idx < 256 ? bm1[idx] : bs1[idx - 256];
  } else if (idx < 1024) {
    int i = idx - 512;
    bcat2[i] = i < 256 ? bm2[i] : bs2[i - 256];
  } else if (idx < 3072) {
    int i = idx - 1024, j = i >> 8, d = i & 255;
    weh1[i] = pack_h2(We1[(2 * j) * 256 + d], We1[(2 * j + 1) * 256 + d]);
  } else if (idx < 5120) {
    int i = idx - 3072, j = i >> 8, d = i & 255;
    weh2[i] = pack_h2(We2[(2 * j) * 256 + d], We2[(2 * j + 1) * 256 + d]);
  }
}

__global__ void ea_pack(const float* __restrict__ ea1,
                        const float* __restrict__ ea2,
                        unsigned int* __restrict__ d1,
                        unsigned int* __restrict__ d2)
{
  int idx = blockIdx.x * 256 + threadIdx.x;  // grid 32768 -> 2*E*8
  const int n = E_TOTAL * 8;
  const float* s;
  unsigned int* d;
  int r;
  if (idx < n) { s = ea1; d = d1; r = idx; }
  else { s = ea2; d = d2; r = idx - n; }
  int e = r >> 3, j = r & 7;
  float2 v = *(const float2*)(s + (size_t)e * 16 + 2 * j);
  d[r] = pack_h2(v.x, v.y);
}

// ---------------------------------------------------------------------------
extern "C" void kernel_launch(void* const* d_in, const int* in_sizes, int n_in,
                              void* d_out, int out_size, void* d_ws, size_t ws_size,
                              hipStream_t stream)
{
  const float* x1 = (const float*)d_in[0];
  const int* ei1 = (const int*)d_in[1];
  const float* ea1 = (const float*)d_in[2];
  const float* x2 = (const float*)d_in[4];
  const int* ei2 = (const int*)d_in[5];
  const float* ea2 = (const float*)d_in[6];
  const float* W0_1 = (const float*)d_in[8];
  const float* b0_1 = (const float*)d_in[9];
  const float* W0_2 = (const float*)d_in[10];
  const float* b0_2 = (const float*)d_in[11];
  const float* Wn1 = (const float*)d_in[12];
  const float* We1 = (const float*)d_in[13];
  const float* bm1 = (const float*)d_in[14];
  const float* Ws1 = (const float*)d_in[15];
  const float* bs1 = (const float*)d_in[16];
  const float* Wn2 = (const float*)d_in[17];
  const float* We2 = (const float*)d_in[18];
  const float* bm2 = (const float*)d_in[19];
  const float* Ws2 = (const float*)d_in[20];
  const float* bs2 = (const float*)d_in[21];
  const float* Wf1 = (const float*)d_in[22];
  const float* bf1 = (const float*)d_in[23];
  const float* Wf2 = (const float*)d_in[24];
  const float* bf2 = (const float*)d_in[25];
  const float* Wo1 = (const float*)d_in[26];
  const float* bo1 = (const float*)d_in[27];
  const float* Wo2 = (const float*)d_in[28];
  const float* bo2 = (const float*)d_in[29];
  float* out = (float*)d_out;

  float* w = (float*)d_ws;
  size_t off = 0;
  auto alloc = [&](size_t nf) { float* p = w + off; off += nf; return p; };
  float* xmA1 = alloc(4194304);
  float* xmA2 = alloc(4194304);
  float* xmB1 = alloc(4194304);
  float* xmB2 = alloc(4194304);
  float* y1 = alloc(8388608);
  float* y2 = alloc(8388608);
  float* R1 = alloc(327680);
  float* R2 = alloc(327680);
  float* outm1 = alloc(65536);
  float* outm2 = alloc(65536);
  float* fusion = alloc(1536);
  float* bcat1 = alloc(512);
  float* bcat2 = alloc(512);
  unsigned short* W0T1 = (unsigned short*)alloc(16384);
  unsigned short* W0T2 = (unsigned short*)alloc(16384);
  unsigned short* WcT1 = (unsigned short*)alloc(65536);
  unsigned short* WcT2 = (unsigned short*)alloc(65536);
  unsigned short* WfT1 = (unsigned short*)alloc(163840);
  unsigned short* WfT2 = (unsigned short*)alloc(163840);
  unsigned int* weh1 = (unsigned int*)alloc(2048);
  unsigned int* weh2 = (unsigned int*)alloc(2048);
  unsigned int* eah1 = (unsigned int*)alloc(4194304);
  unsigned int* eah2 = (unsigned int*)alloc(4194304);
  (void)in_sizes; (void)n_in; (void)out_size; (void)ws_size;

  // ---- prep ----
  transpose_cvt256<<<128, 256, 0, stream>>>(W0_1, W0T1, 128);
  transpose_cvt256<<<128, 256, 0, stream>>>(W0_2, W0T2, 128);
  transpose_cvt256<<<256, 256, 0, stream>>>(Wn1, WcT1, 256);
  transpose_cvt256<<<256, 256, 0, stream>>>(Ws1, WcT1 + 65536, 256);
  transpose_cvt256<<<256, 256, 0, stream>>>(Wn2, WcT2, 256);
  transpose_cvt256<<<256, 256, 0, stream>>>(Ws2, WcT2 + 65536, 256);
  transpose_cvt256<<<1280, 256, 0, stream>>>(Wf1, WfT1, 1280);
  transpose_cvt256<<<1280, 256, 0, stream>>>(Wf2, WfT2, 1280);
  misc_prep<<<20, 256, 0, stream>>>(bm1, bs1, bm2, bs2, We1, We2,
                                    bcat1, bcat2, weh1, weh2);
  ea_pack<<<32768, 256, 0, stream>>>(ea1, ea2, eah1, eah2);

  // ---- embed: xm = rrelu(x @ W0 + b0) ----
  gemm_bf16<<<dim3(128, 2), 256, 0, stream>>>(x1, 128, W0T1, b0_1, xmA1, 256, 128, 2);
  gemm_bf16<<<dim3(128, 2), 256, 0, stream>>>(x2, 128, W0T2, b0_2, xmA2, 256, 128, 2);

  // ---- 3 message-passing steps ----
  float* cur1 = xmA1; float* cur2 = xmA2;
  float* nxt1 = xmB1; float* nxt2 = xmB2;
  for (int step = 0; step < 3; ++step) {
    gemm_bf16<<<dim3(128, 4), 256, 0, stream>>>(cur1, 256, WcT1, bcat1, y1, 512, 256, 0);
    gemm_bf16<<<dim3(128, 4), 256, 0, stream>>>(cur2, 256, WcT2, bcat2, y2, 512, 256, 0);
    edge_conv<<<512, 1024, 0, stream>>>(y1, ei1, eah1, weh1, nxt1);
    edge_conv<<<512, 1024, 0, stream>>>(y2, ei2, eah2, weh2, nxt2);
    dot_pool_k<<<256, 256, 0, stream>>>(nxt1, nxt2, fusion, step);
    float* t1 = cur1; cur1 = nxt1; nxt1 = t1;
    float* t2 = cur2; cur2 = nxt2; nxt2 = t2;
  }

  // ---- readout + head ----
  readout_assemble<<<256, 256, 0, stream>>>(cur1, R1);
  readout_assemble<<<256, 256, 0, stream>>>(cur2, R2);
  gemm_bf16<<<dim3(2, 2), 256, 0, stream>>>(R1, 1280, WfT1, bf1, outm1, 256, 1280, 0);
  gemm_bf16<<<dim3(2, 2), 256, 0, stream>>>(R2, 1280, WfT2, bf2, outm2, 256, 1280, 0);
  final_head<<<256, 256, 0, stream>>>(outm1, outm2, fusion,
                                      Wo1, bo1, Wo2, bo2, out);
}